// Round 12
// baseline (458.897 us; speedup 1.0000x reference)
//
#include <hip/hip_runtime.h>
#include <hip/hip_bf16.h>
#include <hip/hip_cooperative_groups.h>

namespace cg = cooperative_groups;

// Problem constants (B=2,T=64,N=64,D_IN=512,HID=256,L=2,H=4,C=64)
#define NND    64
#define D_IN_  512
#define HID_   256
#define NH     4
#define NCH    64
#define NROWS  8192
#define LN_EPS_ 1e-5f
#define CGRID  256          // cooperative grid: 1 block/CU, always co-resident

typedef __hip_bfloat16 bf16;
typedef __attribute__((ext_vector_type(8))) short short8;   // 8 bf16 = 4 VGPRs
typedef __attribute__((ext_vector_type(4))) float float4v;  // MFMA C/D

struct TrS { float t[32][33]; };                                    // 4.2 KB
struct G1S { bf16 As[64 * 72]; bf16 Bs[64 * 72]; };                 // 18.4 KB
struct G2S { bf16 As[128 * 72]; bf16 Bs[64 * 72]; };                // 27.6 KB
struct AtS {                                                        // 73.2 KB
    float xls [64][68];   // xl row-major [j][c]   (phase 3)
    float xlsT[64][68];   // [c][j]                (phase 1)
    float xrsT[64][68];   // [c][i]                (phase 1)
    float esT [64][68];   // [j][i]
    float av[64], P[64], Q[64], mxf[64], inv[64];
    float pmax[4][64], psum[4][64];
    int   ms[64];
};
union SharedU { TrS tr; G1S g1; G2S g2; AtS at; };

// ===========================================================================
// Phase bodies — shared by the cooperative mega-kernel and the fallback
// multi-kernel path. All unit indices are block-uniform.
// ===========================================================================

// u in [0,385): 384 weight 32x32 transpose tiles + 1 mask-canon unit.
__device__ __forceinline__ void phase_transpose(
    int u, TrS& sh, const float* W_in, const float* Wl, const float* Wr,
    const unsigned int* mw, bf16* WTin, bf16* WlrT, int* mcan)
{
    const int tid = threadIdx.x;
    if (u == 384) {
        for (int i = tid; i < NROWS; i += 256) mcan[i] = (mw[i] != 0u);
        return;
    }
    const float* src; bf16* dst; int K, t;
    if (u < 128) { src = W_in; dst = WTin; K = 512; t = u; }
    else {
        const int idx = u - 128, mat = idx >> 6;   // 0,1:Wl L0/L1  2,3:Wr L0/L1
        t = idx & 63; K = 256;
        const int li = mat & 1; const bool isR = (mat >= 2);
        src = (isR ? Wr : Wl) + li * 65536;
        dst = WlrT + li * 131072 + (isR ? 65536 : 0);
    }
    const int n0 = (t & 7) * 32, k0 = (t >> 3) * 32;
    const int tx = tid & 31, ty = tid >> 5;
    #pragma unroll
    for (int i = 0; i < 4; ++i)
        sh.t[ty + 8 * i][tx] = src[(size_t)(k0 + ty + 8 * i) * 256 + n0 + tx];
    __syncthreads();
    #pragma unroll
    for (int i = 0; i < 4; ++i)
        dst[(size_t)(n0 + ty + 8 * i) * K + k0 + tx] =
            __float2bfloat16(sh.t[tx][ty + 8 * i]);
}

// u in [0,512): input GEMM tile. out = x @ WTin^T + b_in ; hxb = bf16(out).
__device__ __forceinline__ void phase_gemm_in(
    int u, G1S& sh, const float* x, const bf16* WTin, const float* b_in,
    float* out, bf16* hxb)
{
    const int tid = threadIdx.x;
    const int wave = tid >> 6, lane = tid & 63;
    const int quad = lane >> 4, l16 = lane & 15;
    const int m0 = (u >> 2) * 64, n0 = (u & 3) * 64;
    const int wm = (wave & 1) * 32, wn = (wave >> 1) * 32;
    float4v acc[2][2] = {};
    const int r  = tid >> 2;
    const int cq = (tid & 3) * 16;
    for (int k0 = 0; k0 < D_IN_; k0 += 64) {
        const float* sa = x + (size_t)(m0 + r) * D_IN_ + k0 + cq;
        const float4 f0 = *(const float4*)(sa);
        const float4 f1 = *(const float4*)(sa + 4);
        const float4 f2 = *(const float4*)(sa + 8);
        const float4 f3 = *(const float4*)(sa + 12);
        const bf16* sb = WTin + (size_t)(n0 + r) * D_IN_ + k0 + cq;
        const float4 b0 = *(const float4*)(sb);
        const float4 b1 = *(const float4*)(sb + 8);
        union { bf16 hh[16]; float4 v[2]; } uu;
        uu.hh[0]=__float2bfloat16(f0.x); uu.hh[1]=__float2bfloat16(f0.y);
        uu.hh[2]=__float2bfloat16(f0.z); uu.hh[3]=__float2bfloat16(f0.w);
        uu.hh[4]=__float2bfloat16(f1.x); uu.hh[5]=__float2bfloat16(f1.y);
        uu.hh[6]=__float2bfloat16(f1.z); uu.hh[7]=__float2bfloat16(f1.w);
        uu.hh[8]=__float2bfloat16(f2.x); uu.hh[9]=__float2bfloat16(f2.y);
        uu.hh[10]=__float2bfloat16(f2.z); uu.hh[11]=__float2bfloat16(f2.w);
        uu.hh[12]=__float2bfloat16(f3.x); uu.hh[13]=__float2bfloat16(f3.y);
        uu.hh[14]=__float2bfloat16(f3.z); uu.hh[15]=__float2bfloat16(f3.w);
        __syncthreads();
        *(float4*)(&sh.As[r * 72 + cq])     = uu.v[0];
        *(float4*)(&sh.As[r * 72 + cq + 8]) = uu.v[1];
        *(float4*)(&sh.Bs[r * 72 + cq])     = b0;
        *(float4*)(&sh.Bs[r * 72 + cq + 8]) = b1;
        __syncthreads();
        #pragma unroll
        for (int kk = 0; kk < 64; kk += 32) {
            short8 af[2], bf2[2];
            #pragma unroll
            for (int mi = 0; mi < 2; ++mi)
                af[mi] = *(const short8*)(&sh.As[(wm + mi * 16 + l16) * 72 + kk + quad * 8]);
            #pragma unroll
            for (int ni = 0; ni < 2; ++ni)
                bf2[ni] = *(const short8*)(&sh.Bs[(wn + ni * 16 + l16) * 72 + kk + quad * 8]);
            #pragma unroll
            for (int mi = 0; mi < 2; ++mi)
                #pragma unroll
                for (int ni = 0; ni < 2; ++ni)
                    acc[mi][ni] = __builtin_amdgcn_mfma_f32_16x16x32_bf16(
                        af[mi], bf2[ni], acc[mi][ni], 0, 0, 0);
        }
    }
    #pragma unroll
    for (int ni = 0; ni < 2; ++ni) {
        const int col = n0 + wn + ni * 16 + l16;
        const float bv = b_in[col];
        #pragma unroll
        for (int mi = 0; mi < 2; ++mi)
            #pragma unroll
            for (int rr = 0; rr < 4; ++rr) {
                const int row = m0 + wm + mi * 16 + quad * 4 + rr;
                const float v = acc[mi][ni][rr] + bv;
                out[(size_t)row * HID_ + col] = v;
                hxb[(size_t)row * HID_ + col] = __float2bfloat16(v);
            }
    }
}

// u in [0,512): fused xl|xr GEMM tile. [M][512] = hxb @ BT^T + bias.
__device__ __forceinline__ void phase_gemm_lr(
    int u, G2S& sh, const bf16* hxb, const bf16* BT,
    const float* bias0, const float* bias1, float* xlb, float* xrb)
{
    const int tid = threadIdx.x;
    const int wave = tid >> 6, lane = tid & 63;
    const int quad = lane >> 4, l16 = lane & 15;
    const int m0 = (u >> 3) * 128, n0g = (u & 7) * 64;
    const int wm = (wave & 1) * 64, wn = (wave >> 1) * 32;
    float4v acc[4][2] = {};
    const int r  = tid >> 2;
    const int cq = (tid & 3) * 16;
    for (int k0 = 0; k0 < HID_; k0 += 64) {
        const bf16* sa0 = hxb + (size_t)(m0 + r) * HID_ + k0 + cq;
        const bf16* sa1 = sa0 + (size_t)64 * HID_;
        const bf16* sb  = BT + (size_t)(n0g + r) * HID_ + k0 + cq;
        const float4 a00 = *(const float4*)(sa0);
        const float4 a01 = *(const float4*)(sa0 + 8);
        const float4 a10 = *(const float4*)(sa1);
        const float4 a11 = *(const float4*)(sa1 + 8);
        const float4 b0  = *(const float4*)(sb);
        const float4 b1  = *(const float4*)(sb + 8);
        __syncthreads();
        *(float4*)(&sh.As[r * 72 + cq])            = a00;
        *(float4*)(&sh.As[r * 72 + cq + 8])        = a01;
        *(float4*)(&sh.As[(r + 64) * 72 + cq])     = a10;
        *(float4*)(&sh.As[(r + 64) * 72 + cq + 8]) = a11;
        *(float4*)(&sh.Bs[r * 72 + cq])            = b0;
        *(float4*)(&sh.Bs[r * 72 + cq + 8])        = b1;
        __syncthreads();
        #pragma unroll
        for (int kk = 0; kk < 64; kk += 32) {
            short8 af[4], bf2[2];
            #pragma unroll
            for (int mi = 0; mi < 4; ++mi)
                af[mi] = *(const short8*)(&sh.As[(wm + mi * 16 + l16) * 72 + kk + quad * 8]);
            #pragma unroll
            for (int ni = 0; ni < 2; ++ni)
                bf2[ni] = *(const short8*)(&sh.Bs[(wn + ni * 16 + l16) * 72 + kk + quad * 8]);
            #pragma unroll
            for (int mi = 0; mi < 4; ++mi)
                #pragma unroll
                for (int ni = 0; ni < 2; ++ni)
                    acc[mi][ni] = __builtin_amdgcn_mfma_f32_16x16x32_bf16(
                        af[mi], bf2[ni], acc[mi][ni], 0, 0, 0);
        }
    }
    const bool loHalf = (n0g < 256);
    float* Co = loHalf ? xlb : xrb;
    const float* bp = loHalf ? bias0 : bias1;
    const int cbase = loHalf ? n0g : (n0g - 256);
    #pragma unroll
    for (int ni = 0; ni < 2; ++ni) {
        const int col = cbase + wn + ni * 16 + l16;
        const float bv = bp[col];
        #pragma unroll
        for (int mi = 0; mi < 4; ++mi)
            #pragma unroll
            for (int rr = 0; rr < 4; ++rr) {
                const int row = m0 + wm + mi * 16 + quad * 4 + rr;
                Co[(size_t)row * 256 + col] = acc[mi][ni][rr] + bv;
            }
    }
}

// u in [0,512): attention per (graph, head). gb MAY ALIAS xrb: each unit
// fully stages its xr slice into LDS before writing, and unit v's slice is
// only written by unit v, so stride-looped blocks stay race-free.
__device__ __forceinline__ void phase_attn(
    int u, AtS& sh, const float* xlb, const float* xrb, const float* attL,
    const int* mcan, float* gb)
{
    const int tid = threadIdx.x;
    const int head = u & 3, gr = u >> 2;
    const int ti = tid >> 4, tj = tid & 15;
    const int i0 = ti * 4, j0 = tj * 4;
    const float* xlg = xlb + (size_t)gr * NND * HID_ + head * NCH;
    const float* xrg = xrb + (size_t)gr * NND * HID_ + head * NCH;
    {
        const int r  = tid >> 2;
        const int c0 = (tid & 3) * 16;
        float a[4][4], b[4][4];
        #pragma unroll
        for (int k = 0; k < 4; ++k) {
            *(float4*)a[k] = *(const float4*)(xlg + r * HID_ + c0 + 4 * k);
            *(float4*)b[k] = *(const float4*)(xrg + r * HID_ + c0 + 4 * k);
        }
        #pragma unroll
        for (int k = 0; k < 4; ++k)
            *(float4*)&sh.xls[r][c0 + 4 * k] = *(float4*)a[k];
        #pragma unroll
        for (int k = 0; k < 4; ++k)
            #pragma unroll
            for (int w = 0; w < 4; ++w) {
                sh.xlsT[c0 + 4 * k + w][r] = a[k][w];
                sh.xrsT[c0 + 4 * k + w][r] = b[k][w];
            }
    }
    if (tid < 64) {
        sh.av[tid] = attL[head * NCH + tid];
        sh.ms[tid] = mcan[gr * NND + tid];
    }
    __syncthreads();

    float aa[4][4] = {};
    for (int c = 0; c < 64; ++c) {
        float xr4[4], xl4[4];
        *(float4*)xr4 = *(const float4*)&sh.xrsT[c][i0];
        *(float4*)xl4 = *(const float4*)&sh.xlsT[c][j0];
        const float a = sh.av[c];
        #pragma unroll
        for (int y = 0; y < 4; ++y)
            #pragma unroll
            for (int xx = 0; xx < 4; ++xx)
                aa[y][xx] = fmaf(a, fabsf(xr4[y] + xl4[xx]), aa[y][xx]);
    }
    if (tid < 64) {
        float s = 0.f;
        for (int c = 0; c < 64; ++c) s = fmaf(sh.av[c], sh.xrsT[c][tid], s);
        sh.P[tid] = s;
    } else if (tid < 128) {
        const int j = tid - 64;
        float s = 0.f;
        for (int c = 0; c < 64; ++c) s = fmaf(sh.av[c], sh.xlsT[c][j], s);
        sh.Q[j] = s;
    }
    __syncthreads();

    {
        float Pv[4], Qv[4]; int mi4[4], mj4[4];
        #pragma unroll
        for (int y = 0; y < 4; ++y) { Pv[y] = sh.P[i0 + y]; mi4[y] = sh.ms[i0 + y]; }
        #pragma unroll
        for (int xx = 0; xx < 4; ++xx) { Qv[xx] = sh.Q[j0 + xx]; mj4[xx] = sh.ms[j0 + xx]; }
        #pragma unroll
        for (int xx = 0; xx < 4; ++xx) {
            float col[4];
            #pragma unroll
            for (int y = 0; y < 4; ++y) {
                float e = fmaf(0.4f, aa[y][xx], 0.6f * (Pv[y] + Qv[xx]));
                const bool allowed = (mi4[y] && mj4[xx]) || (i0 + y == j0 + xx);
                col[y] = allowed ? e : -1e9f;
            }
            *(float4*)&sh.esT[j0 + xx][i0] = *(float4*)col;
        }
    }
    __syncthreads();

    {
        const int si = tid & 63, q = tid >> 6;
        float mx = -1e30f;
        #pragma unroll
        for (int k = 0; k < 16; ++k) mx = fmaxf(mx, sh.esT[16 * q + k][si]);
        sh.pmax[q][si] = mx;
    }
    __syncthreads();
    if (tid < 64)
        sh.mxf[tid] = fmaxf(fmaxf(sh.pmax[0][tid], sh.pmax[1][tid]),
                            fmaxf(sh.pmax[2][tid], sh.pmax[3][tid]));
    __syncthreads();
    {
        const int si = tid & 63, q = tid >> 6;
        const float mx = sh.mxf[si];
        float s = 0.f;
        #pragma unroll
        for (int k = 0; k < 16; ++k) {
            const float ev = __expf(sh.esT[16 * q + k][si] - mx);
            sh.esT[16 * q + k][si] = ev;
            s += ev;
        }
        sh.psum[q][si] = s;
    }
    __syncthreads();
    if (tid < 64)
        sh.inv[tid] = 1.f / (sh.psum[0][tid] + sh.psum[1][tid] +
                             sh.psum[2][tid] + sh.psum[3][tid]);
    __syncthreads();

    {
        const int c0 = j0;
        float oa[4][4] = {};
        for (int j = 0; j < 64; ++j) {
            float al[4], xv[4];
            *(float4*)al = *(const float4*)&sh.esT[j][i0];
            *(float4*)xv = *(const float4*)&sh.xls[j][c0];
            #pragma unroll
            for (int y = 0; y < 4; ++y)
                #pragma unroll
                for (int xx = 0; xx < 4; ++xx)
                    oa[y][xx] = fmaf(al[y], xv[xx], oa[y][xx]);
        }
        #pragma unroll
        for (int y = 0; y < 4; ++y) {
            const float iv = sh.inv[i0 + y];
            float o[4];
            #pragma unroll
            for (int xx = 0; xx < 4; ++xx) o[xx] = oa[y][xx] * iv;
            float* go = gb + (size_t)(gr * NND + i0 + y) * HID_ + head * NCH + c0;
            *(float4*)go = *(float4*)o;
        }
    }
}

// u in [0,2048): epilogue for rows 4u..4u+3 (one wave per row). No LDS.
__device__ __forceinline__ void phase_epi(
    int u, const float* gb, const float* res, const float* obp,
    const float* lsp, const float* lbp, const int* mcan,
    float* hout, bf16* hb, int finalSel)
{
    const int lane = threadIdx.x & 63;
    const int wave = threadIdx.x >> 6;
    const int m = u * 4 + wave;
    if (finalSel) {
        const int gr = m >> 6;
        const unsigned long long bal = __ballot(mcan[gr * NND + lane] != 0);
        if (__popcll(bal) <= 1) return;   // leave h0 rows in d_out
    }
    const float* grow = gb + (size_t)m * HID_;
    float v[4];
    float sum = 0.f;
    #pragma unroll
    for (int q = 0; q < 4; ++q) {
        const int c = q * 64 + lane;
        float xv = grow[c] + obp[c];
        xv = xv > 0.f ? xv : (__expf(xv) - 1.f);   // ELU (alpha=1)
        v[q] = xv; sum += xv;
    }
    #pragma unroll
    for (int off = 1; off < 64; off <<= 1) sum += __shfl_xor(sum, off);
    const float mu = sum * (1.f / 256.f);
    float vs = 0.f;
    #pragma unroll
    for (int q = 0; q < 4; ++q) { const float d = v[q] - mu; vs += d * d; }
    #pragma unroll
    for (int off = 1; off < 64; off <<= 1) vs += __shfl_xor(vs, off);
    const float rstd = rsqrtf(vs * (1.f / 256.f) + LN_EPS_);
    const int mnode = mcan[m];
    const float* rrow = res + (size_t)m * HID_;
    float* ho = hout + (size_t)m * HID_;
    #pragma unroll
    for (int q = 0; q < 4; ++q) {
        const int c = q * 64 + lane;
        float y = (v[q] - mu) * rstd * lsp[c] + lbp[c];
        y += rrow[c];
        y = mnode ? y : 0.f;
        ho[c] = y;
        if (hb) hb[(size_t)m * HID_ + c] = __float2bfloat16(y);
    }
}

// ===========================================================================
// Cooperative mega-kernel (grid = CGRID blocks, stride loops per phase)
// ===========================================================================
__global__ __launch_bounds__(256, 2) void fused_kernel(
    const float* x, const unsigned int* mw,
    const float* W_in, const float* b_in,
    const float* Wl, const float* bl,
    const float* Wr, const float* br,
    const float* att, const float* ob,
    const float* lns, const float* lnb,
    float* out, int* mcan, float* h, float* xlb, float* xrb,
    bf16* hxb, bf16* WTin, bf16* WlrT)
{
    __shared__ SharedU sh;
    cg::grid_group grid = cg::this_grid();
    const int bid = blockIdx.x;

    for (int u = bid; u < 385; u += CGRID) {
        phase_transpose(u, sh.tr, W_in, Wl, Wr, mw, WTin, WlrT, mcan);
        __syncthreads();
    }
    grid.sync();

    for (int u = bid; u < 512; u += CGRID) {
        phase_gemm_in(u, sh.g1, x, WTin, b_in, out, hxb);
        __syncthreads();
    }
    grid.sync();

    for (int li = 0; li < 2; ++li) {
        const bf16* BT = WlrT + (size_t)li * 131072;
        for (int u = bid; u < 512; u += CGRID) {
            phase_gemm_lr(u, sh.g2, hxb, BT, bl + li * HID_, br + li * HID_,
                          xlb, xrb);
            __syncthreads();
        }
        grid.sync();
        for (int u = bid; u < 512; u += CGRID) {
            phase_attn(u, sh.at, xlb, xrb, att + li * NH * NCH, mcan, xrb);
            __syncthreads();
        }
        grid.sync();
        const float* res = (li == 0) ? out : h;
        float* hout = (li == 0) ? h : out;
        for (int u = bid; u < 2048; u += CGRID)
            phase_epi(u, xrb, res, ob + li * HID_, lns + li * HID_,
                      lnb + li * HID_, mcan, hout,
                      (li == 0) ? hxb : (bf16*)nullptr, li);
        if (li == 0) grid.sync();
    }
}

// ===========================================================================
// Fallback standalone kernels (R9-equivalent path, same phase bodies)
// ===========================================================================
__global__ __launch_bounds__(256) void k_transpose(
    const float* W_in, const float* Wl, const float* Wr,
    const unsigned int* mw, bf16* WTin, bf16* WlrT, int* mcan) {
    __shared__ TrS sh;
    phase_transpose(blockIdx.x, sh, W_in, Wl, Wr, mw, WTin, WlrT, mcan);
}
__global__ __launch_bounds__(256) void k_gemm_in(
    const float* x, const bf16* WTin, const float* b_in,
    float* out, bf16* hxb) {
    __shared__ G1S sh;
    phase_gemm_in(blockIdx.x, sh, x, WTin, b_in, out, hxb);
}
__global__ __launch_bounds__(256) void k_gemm_lr(
    const bf16* hxb, const bf16* BT, const float* bias0, const float* bias1,
    float* xlb, float* xrb) {
    __shared__ G2S sh;
    phase_gemm_lr(blockIdx.x, sh, hxb, BT, bias0, bias1, xlb, xrb);
}
__global__ __launch_bounds__(256) void k_attn(
    const float* xlb, const float* xrb, const float* attL,
    const int* mcan, float* gb) {
    __shared__ AtS sh;
    phase_attn(blockIdx.x, sh, xlb, xrb, attL, mcan, gb);
}
__global__ __launch_bounds__(256) void k_epi(
    const float* gb, const float* res, const float* obp, const float* lsp,
    const float* lbp, const int* mcan, float* hout, bf16* hb, int finalSel) {
    phase_epi(blockIdx.x, gb, res, obp, lsp, lbp, mcan, hout, hb, finalSel);
}

// ---------------------------------------------------------------------------
extern "C" void kernel_launch(void* const* d_in, const int* in_sizes, int n_in,
                              void* d_out, int out_size, void* d_ws, size_t ws_size,
                              hipStream_t stream) {
    const float* x    = (const float*)d_in[0];
    const unsigned int* mw = (const unsigned int*)d_in[1];
    const float* W_in = (const float*)d_in[2];
    const float* b_in = (const float*)d_in[3];
    const float* Wl   = (const float*)d_in[4];
    const float* bl   = (const float*)d_in[5];
    const float* Wr   = (const float*)d_in[6];
    const float* br   = (const float*)d_in[7];
    const float* att  = (const float*)d_in[8];
    const float* ob   = (const float*)d_in[9];
    const float* lns  = (const float*)d_in[10];
    const float* lnb  = (const float*)d_in[11];
    float* out = (float*)d_out;

    // ws (~29 MB): [mcan 32K][h 8M][xlb 8M][xrb 8M][hxb 4M][WTin 256K][WlrT 512K]
    char* w = (char*)d_ws;
    int*   mcan = (int*)w;                      w += 32768;
    float* h    = (float*)w;                    w += (size_t)NROWS * HID_ * 4;
    float* xlb  = (float*)w;                    w += (size_t)NROWS * HID_ * 4;
    float* xrb  = (float*)w;                    w += (size_t)NROWS * HID_ * 4;
    bf16*  hxb  = (bf16*)w;                     w += (size_t)NROWS * HID_ * 2;
    bf16*  WTin = (bf16*)w;                     w += (size_t)D_IN_ * HID_ * 2;
    bf16*  WlrT = (bf16*)w;                     // [L][512][256]

    void* args[] = { &x, &mw, &W_in, &b_in, &Wl, &bl, &Wr, &br, &att, &ob,
                     &lns, &lnb, &out, &mcan, &h, &xlb, &xrb, &hxb, &WTin, &WlrT };
    hipError_t err = hipLaunchCooperativeKernel(
        (const void*)fused_kernel, dim3(CGRID), dim3(256), args, 0, stream);

    if (err != hipSuccess) {
        (void)hipGetLastError();   // clear sticky error, take fallback path
        k_transpose<<<385, 256, 0, stream>>>(W_in, Wl, Wr, mw, WTin, WlrT, mcan);
        k_gemm_in<<<512, 256, 0, stream>>>(x, WTin, b_in, out, hxb);
        for (int li = 0; li < 2; ++li) {
            k_gemm_lr<<<512, 256, 0, stream>>>(
                hxb, WlrT + (size_t)li * 131072, bl + li * HID_, br + li * HID_,
                xlb, xrb);
            k_attn<<<512, 256, 0, stream>>>(
                xlb, xrb, att + li * NH * NCH, mcan, xrb);
            const float* res = (li == 0) ? out : h;
            float* hout = (li == 0) ? h : out;
            k_epi<<<2048, 256, 0, stream>>>(
                xrb, res, ob + li * HID_, lns + li * HID_, lnb + li * HID_,
                mcan, hout, (li == 0) ? hxb : (bf16*)nullptr, li);
        }
    }

    (void)in_sizes; (void)n_in; (void)out_size; (void)ws_size;
}